// Round 10
// baseline (96.700 us; speedup 1.0000x reference)
//
#include <hip/hip_runtime.h>
#include <math.h>

#define TOK 4096
#define DM  512
#define HF  2048
#define NE  8
// Padded row strides (+32 elems = +64 B). Round-7 measured this as perf-null,
// but it is kept (harmless, and removes any channel-alias doubt).
#define PD 544     // padded stride for rows of DM elems (xb, W1t)
#define PH 2080    // padded stride for rows of HF elems (hg, W2t)

typedef __bf16 bf16x8 __attribute__((ext_vector_type(8)));
typedef float  floatx16 __attribute__((ext_vector_type(16)));
typedef float  f4n __attribute__((ext_vector_type(4)));   // clang vector: OK for nontemporal builtins

// float -> bf16 (round-to-nearest-even), raw ushort bits
__device__ __forceinline__ unsigned short f2b(float f) {
    union { float f; unsigned u; } v; v.f = f;
    return (unsigned short)((v.u + 0x7fffu + ((v.u >> 16) & 1u)) >> 16);
}

// async global->LDS, 16 bytes per lane (dest = wave-uniform base + lane*16,
// global source address is PER-LANE -> used for perm-indirect A gather in fc1)
__device__ __forceinline__ void load_lds16(const void* g, void* l) {
    __builtin_amdgcn_global_load_lds(
        (__attribute__((address_space(1))) unsigned int*)g,
        (__attribute__((address_space(3))) unsigned int*)l, 16, 0, 0);
}

// 64x64 fp32->bf16 transpose tile; tile buffer passed in so callers can
// OVERLAY it on other LDS (disjoint lifetime). dst row stride dstS (padded).
template <int NTHR>
__device__ __forceinline__ void transpose_tile(unsigned short (*tile)[68],
                                               const float* __restrict__ src,
                                               unsigned short* __restrict__ dst,
                                               int K, int N, int dstS,
                                               int k0, int n0) {
#pragma unroll
    for (int i = 0; i < 1024 / NTHR; i++) {
        int it = threadIdx.x + i * NTHR;
        int r = it >> 4, tc = it & 15;
        const float4 v = *(const float4*)(src + (size_t)(k0 + r) * N + n0 + tc * 4);
        tile[r][tc * 4 + 0] = f2b(v.x);
        tile[r][tc * 4 + 1] = f2b(v.y);
        tile[r][tc * 4 + 2] = f2b(v.z);
        tile[r][tc * 4 + 3] = f2b(v.w);
    }
    __syncthreads();
#pragma unroll
    for (int i = 0; i < 1024 / NTHR; i++) {
        int it = threadIdx.x + i * NTHR;
        int nrow = it >> 4, tc = it & 15;
        ushort4 o;
        o.x = tile[tc * 4 + 0][nrow];
        o.y = tile[tc * 4 + 1][nrow];
        o.z = tile[tc * 4 + 2][nrow];
        o.w = tile[tc * 4 + 3][nrow];
        *(ushort4*)(dst + (size_t)(n0 + nrow) * dstS + k0 + tc * 4) = o;
    }
}

// Fused: router (blocks 0..1023, one wave per token) + W1 transpose (2048 blocks,
// XCD-PINNED: transpose block for expert e has id%8==e).
// Router also emits xb = bf16(x) in TOKEN order (padded rows PD).
__global__ __launch_bounds__(256)
void k_router_trW1(const float* __restrict__ x, const float* __restrict__ Wr,
                   const float* __restrict__ br, const float* __restrict__ W1,
                   int* __restrict__ routes, unsigned short* __restrict__ xb,
                   unsigned short* __restrict__ W1t) {
    if (blockIdx.x >= TOK / 4) {            // W1: [E][512][2048] -> [E][2048][PD]
        __shared__ unsigned short tl[64][68];
        int bt = blockIdx.x - TOK / 4;      // 1024%8==0 -> id%8 == bt%8 == e
        int e = bt & 7, tile = bt >> 3;     // 8 k-tiles x 32 n-tiles
        transpose_tile<256>(tl, W1 + (size_t)e * DM * HF, W1t + (size_t)e * HF * PD,
                            DM, HF, PD, (tile >> 5) * 64, (tile & 31) * 64);
        return;
    }
    int t = blockIdx.x * 4 + (threadIdx.x >> 6);
    int lane = threadIdx.x & 63;
    const float4* xr = (const float4*)(x + (size_t)t * DM);
    float4 v0 = xr[lane * 2 + 0];           // 8 consecutive d per lane
    float4 v1 = xr[lane * 2 + 1];
    float xv[8] = {v0.x, v0.y, v0.z, v0.w, v1.x, v1.y, v1.z, v1.w};

    union { unsigned short u[8]; int4 q; } pk;
#pragma unroll
    for (int k = 0; k < 8; k++) pk.u[k] = f2b(xv[k]);
    *(int4*)(xb + (size_t)t * PD + lane * 8) = pk.q;   // coalesced 16B/lane

    float acc[NE];
#pragma unroll
    for (int e = 0; e < NE; e++) acc[e] = 0.f;
#pragma unroll
    for (int k = 0; k < 8; k++) {
        const float* w = Wr + (size_t)(lane * 8 + k) * NE;
        float4 wa = *(const float4*)(w);
        float4 wb = *(const float4*)(w + 4);
        acc[0] += xv[k] * wa.x; acc[1] += xv[k] * wa.y;
        acc[2] += xv[k] * wa.z; acc[3] += xv[k] * wa.w;
        acc[4] += xv[k] * wb.x; acc[5] += xv[k] * wb.y;
        acc[6] += xv[k] * wb.z; acc[7] += xv[k] * wb.w;
    }
#pragma unroll
    for (int off = 32; off > 0; off >>= 1)
#pragma unroll
        for (int e = 0; e < NE; e++) acc[e] += __shfl_down(acc[e], off, 64);
    if (lane == 0) {
        int best = 0; float bv = acc[0] + br[0];
#pragma unroll
        for (int e = 1; e < NE; e++) {
            float v = acc[e] + br[e];
            if (v > bv) { bv = v; best = e; }   // strict > == first-max (jnp.argmax)
        }
        routes[t] = best;
    }
}

// Organize only (1 block): ballot-based histogram + prefix + perm, zero atomics.
__global__ __launch_bounds__(1024)
void k_organize(const int* __restrict__ routes, int* __restrict__ offsets,
                int* __restrict__ perm) {
    __shared__ int wcnt[16][NE], wbase[16][NE], off[NE + 1], tot[NE];
    int tid = threadIdx.x, lane = tid & 63, w = tid >> 6;
    int4 r4 = *(const int4*)&routes[tid * 4];
    int e_[4] = {r4.x, r4.y, r4.z, r4.w};
    unsigned long long below = (1ull << lane) - 1ull;
    int rank[4];
#pragma unroll
    for (int e = 0; e < NE; e++) {
        int c = 0;
#pragma unroll
        for (int j = 0; j < 4; j++) {
            unsigned long long m = __ballot(e_[j] == e);
            if (e_[j] == e) rank[j] = c + __popcll(m & below);
            c += __popcll(m);
        }
        if (lane == 0) wcnt[w][e] = c;
    }
    __syncthreads();
    if (tid < NE) {                          // prefix over waves, per expert
        int s = 0;
#pragma unroll
        for (int ww = 0; ww < 16; ww++) { wbase[ww][tid] = s; s += wcnt[ww][tid]; }
        tot[tid] = s;
    }
    __syncthreads();
    if (tid == 0) {
        int s = 0;
#pragma unroll
        for (int e = 0; e < NE; e++) { off[e] = s; s += tot[e]; }
        off[NE] = s;
    }
    __syncthreads();
#pragma unroll
    for (int j = 0; j < 4; j++) {
        int e = e_[j];
        perm[off[e] + wbase[w][e] + rank[j]] = tid * 4 + j;
    }
    if (tid < NE + 1) offsets[tid] = off[tid];
}

// Grouped GEMM: 64x128 block, 4 waves (2Mx2N) of 32x64, BK=32, dbuf LDS 24 KB,
// XOR bank swizzle, plain __syncthreads protocol, expert->XCD 1D grid
// (id%8==e). Round-8/9 changes (loop untouched):
//  (a) FC1 id INTERLEAVE: id = 16*g + cls*8 + e. cls=1 -> W2-transpose tile g
//      for expert e; cls=0 -> GEMM tile g (by=g>>4, bx=g&15). Previously all
//      2048 transpose blocks had the HIGHEST ids -> they dispatched after the
//      GEMM drained = a ~100 MB serial TAIL (~12-15 us). Interleaving makes
//      them co-resident with the latency-bound GEMM -> transpose BW fills the
//      GEMM's idle memory pipe. id%8==e preserved for both classes.
//  (b) FC2 partial stores / k_reduce loads / out stores are NONTEMPORAL:
//      pbuf+out are streaming (written once, read once) -- stop them evicting
//      the hg/W2t panels from the 4 MB XCD-L2 (fc2's measured thrash: 27.5 MB
//      re-FETCH of its own operands).
// FC2 KSPLIT=2 (was 4): pbuf traffic halves; K-slice 1024 = 32 iters.
template <int KD, int KP, int ND, bool FC1, int KSPLIT, int XT, int YT>
__global__ __launch_bounds__(256)
void k_gemm(const unsigned short* __restrict__ A,
            const unsigned short* __restrict__ Bt,
            const float* __restrict__ bias,
            unsigned short* __restrict__ hg,
            float* __restrict__ pbuf,
            const int* __restrict__ offsets,
            const int* __restrict__ perm,
            const float* __restrict__ W2s,
            unsigned short* __restrict__ W2d) {
    __shared__ unsigned short smem[12288];   // 2 bufs x (A 64x32 + B 128x32) = 24 KB

    const int id = blockIdx.x;
    int e, bx, by, ks;
    if constexpr (FC1) {
        // interleaved classes: cls = (id>>3)&1, e = id&7, g = id>>4
        int g = id >> 4;
        e = id & 7;
        if ((id >> 3) & 1) {                // W2: [E][2048][512] -> [E][512][PH]
            transpose_tile<256>((unsigned short(*)[68])smem,   // LDS overlay
                                W2s + (size_t)e * HF * DM, W2d + (size_t)e * DM * PH,
                                HF, DM, PH, (g >> 3) * 64, (g & 7) * 64);
            return;
        }
        bx = g & (XT - 1);                  // XT=16
        by = g >> 4;                        // YT=16
        ks = 0;
    } else {
        e = id & 7;
        int t = id >> 3;
        ks = t % KSPLIT; t /= KSPLIT;
        bx = t % XT;
        by = t / XT;
    }

    const int seg0 = offsets[e];
    const int cnt  = offsets[e + 1] - seg0;
    const int m0 = by * 64;
    if (m0 >= cnt) return;
    const int n0 = bx * 128;

    const unsigned short* Bexp = Bt + (size_t)e * ND * KP;

    const int tid  = threadIdx.x;
    const int lane = tid & 63;
    const int wave = tid >> 6;
    const int wm = (wave >> 1) * 32;   // wave M offset in 64-row block tile
    const int wn = (wave & 1) * 64;    // wave N offset in 128-col block tile

    // staging sources, hoisted (k-invariant). phys slot (row = fo>>6,
    // pc = (fo>>4)&3) holds global chunk c = pc ^ ((row>>1)&3).
    const unsigned short* aSrc;        // A tile 64x32 = 4 KB -> 1 chunk/thread
    const unsigned short* bSrc[2];     // B tile 128x32 = 8 KB -> 2 chunks/thread
    const int foA = tid * 16;
    {
        int row = foA >> 6;
        int c   = ((foA >> 4) & 3) ^ ((row >> 1) & 3);
        if constexpr (FC1) {
            int idx = seg0 + m0 + row;             // clamp: tail rows never stored
            if (idx > TOK - 1) idx = TOK - 1;
            aSrc = A + (size_t)perm[idx] * KP + c * 8;   // token-order xb
        } else {
            aSrc = A + (size_t)(seg0 + m0 + row) * KP + c * 8;  // grouped hg
        }
    }
    int foB[2];
#pragma unroll
    for (int r = 0; r < 2; r++) {
        int fo  = tid * 16 + r * 4096;
        int row = fo >> 6;
        int c   = ((fo >> 4) & 3) ^ ((row >> 1) & 3);
        foB[r] = fo;
        bSrc[r] = Bexp + (size_t)(n0 + row) * KP + c * 8;
    }
    auto stage = [&](int k0, int buf) {
        char* ab = (char*)(smem + buf * 6144);
        char* bb = (char*)(smem + buf * 6144 + 2048);
        load_lds16(aSrc + k0, ab + foA);
#pragma unroll
        for (int r = 0; r < 2; r++) load_lds16(bSrc[r] + k0, bb + foB[r]);
    };

    // fragment read addressing (32x32x16: m/n = lane&31, k = (lane>>5)*8 + j)
    const int fr = lane & 31;
    const int hi = lane >> 5;
    const int q  = (lane >> 1) & 3;
    const int sw[2] = { ((0 + hi) ^ q) * 8, ((2 + hi) ^ q) * 8 };
    const int aBase = (wm + fr) * 32;
    const int bBase = (wn + fr) * 32;

    floatx16 acc[2];
#pragma unroll
    for (int j = 0; j < 2; j++)
#pragma unroll
        for (int r = 0; r < 16; r++) acc[j][r] = 0.f;

    const int kBase = ks * (KD / KSPLIT);
    const int kEnd  = kBase + (KD / KSPLIT);
    stage(kBase, 0);
    int cur = 0;
    for (int k0 = kBase; k0 < kEnd; k0 += 32) {
        __syncthreads();   // buf `cur` staged; prior reads of cur^1 done
        if (k0 + 32 < kEnd) stage(k0 + 32, cur ^ 1);   // prefetch overlaps MFMA
        const unsigned short* Ab = smem + cur * 6144;
        const unsigned short* Bb = smem + cur * 6144 + 2048;
#pragma unroll
        for (int kk = 0; kk < 2; kk++) {
            bf16x8 af = *(const bf16x8*)&Ab[aBase + sw[kk]];
            bf16x8 bf[2];
#pragma unroll
            for (int j = 0; j < 2; j++)
                bf[j] = *(const bf16x8*)&Bb[bBase + j * 1024 + sw[kk]];
#pragma unroll
            for (int j = 0; j < 2; j++)
                acc[j] = __builtin_amdgcn_mfma_f32_32x32x16_bf16(af, bf[j], acc[j], 0, 0, 0);
        }
        cur ^= 1;
    }

    // epilogue: 32x32 C/D layout col=lane&31, row=(reg&3)+8*(reg>>2)+4*(lane>>5)
    const int rbase = 4 * hi;
#pragma unroll
    for (int j = 0; j < 2; j++) {
        int col = n0 + wn + j * 32 + fr;
        float bv = FC1 ? bias[(size_t)e * ND + col] : 0.f;
#pragma unroll
        for (int r = 0; r < 16; r++) {
            int grow = m0 + wm + rbase + (r & 3) + 8 * (r >> 2);
            if (grow < cnt) {
                float v = acc[j][r] + bv;
                if constexpr (FC1) {
                    v = 0.5f * v * (1.0f + erff(v * 0.70710678118654752f)); // exact GELU
                    hg[(size_t)(seg0 + grow) * PH + col] = f2b(v);
                } else {
                    // streaming partial: nontemporal, don't evict hg/W2t panels
                    __builtin_nontemporal_store(
                        v, &pbuf[((size_t)ks * TOK + seg0 + grow) * ND + col]);
                }
            }
        }
    }
}

// out[perm[g]][:] = sum_ks pbuf[ks][g][:] + b2[e(g)][:]   (KSPLIT=2)
__global__ __launch_bounds__(128)
void k_reduce(const float* __restrict__ pbuf, const int* __restrict__ perm,
              const int* __restrict__ offsets, const float* __restrict__ b2,
              float* __restrict__ out) {
    int g = blockIdx.x;
    int tok = perm[g];
    int e = 0;
#pragma unroll
    for (int i = 1; i < NE; i++) e += (g >= offsets[i]);
    int c = threadIdx.x * 4;
    f4n o = *(const f4n*)&b2[(size_t)e * DM + c];
#pragma unroll
    for (int ks = 0; ks < 2; ks++) {
        const f4n* p = (const f4n*)&pbuf[((size_t)ks * TOK + g) * DM + c];
        f4n a = __builtin_nontemporal_load(p);
        o += a;
    }
    __builtin_nontemporal_store(o, (f4n*)&out[(size_t)tok * DM + c]);
}

extern "C" void kernel_launch(void* const* d_in, const int* in_sizes, int n_in,
                              void* d_out, int out_size, void* d_ws, size_t ws_size,
                              hipStream_t stream) {
    const float* x  = (const float*)d_in[0];
    const float* Wr = (const float*)d_in[1];
    const float* br = (const float*)d_in[2];
    const float* W1 = (const float*)d_in[3];
    const float* b1 = (const float*)d_in[4];
    const float* W2 = (const float*)d_in[5];
    const float* b2 = (const float*)d_in[6];
    float* out = (float*)d_out;

    char* ws = (char*)d_ws;
    int* routes  = (int*)ws;            // [4096]
    int* perm    = routes + TOK;        // [4096]
    int* offsets = perm + TOK;          // [9]
    unsigned short* xb  = (unsigned short*)(ws + 65536);     // [4096][PD]  bf16 token-order (4.5 MB)
    unsigned short* hg  = xb + (size_t)TOK * PD;             // [4096][PH]  bf16 grouped (17 MB)
    unsigned short* W1t = hg + (size_t)TOK * PH;             // [E][HF][PD] bf16 (17.8 MB)
    unsigned short* W2t = W1t + (size_t)NE * HF * PD;        // [E][DM][PH] bf16 (17 MB)
    float* pbuf = (float*)(W2t + (size_t)NE * DM * PH);      // [2][4096][512] fp32 (16.8 MB)
    // FC2 A-tile overruns past hg end land in W1t (valid memory, non-NaN bf16);
    // rows >= cnt never stored. FC1 A rows are perm-clamped (no overrun).
    // YT=16 with 64-row tiles covers cnt up to 1024 (>20 sigma above 512 mean).

    // 1: router (+ token-order bf16 x, padded rows) || W1 transpose (XCD-pinned)
    k_router_trW1<<<TOK / 4 + 2048, 256, 0, stream>>>(x, Wr, br, W1, routes, xb, W1t);
    // 2: ballot organize (1 block, ~2 us)
    k_organize<<<1, 1024, 0, stream>>>(routes, offsets, perm);
    // 3: fc1 (perm-gather in A staging), 64x128 tiles, INTERLEAVED with the
    //    W2 transpose (id = 16g + cls*8 + e): 2048 GEMM + 2048 transpose = 4096
    k_gemm<DM, PD, HF, true, 1, 16, 16><<<4096, 256, 0, stream>>>(
        xb, W1t, b1, hg, nullptr, offsets, perm, W2, W2t);
    // 4: fc2, split-K=2, 64x128 tiles, expert->XCD 1D grid (4x * 16y * 2ks)
    k_gemm<HF, PH, DM, false, 2, 4, 16><<<NE * 128, 256, 0, stream>>>(
        hg, W2t, nullptr, nullptr, pbuf, offsets, perm, nullptr, nullptr);
    // 5: reduce + bias + scatter (2 partials, nontemporal)
    k_reduce<<<TOK, 128, 0, stream>>>(pbuf, perm, offsets, b2, out);
}

// Round 11
// 86.941 us; speedup vs baseline: 1.1122x; 1.1122x over previous
//
#include <hip/hip_runtime.h>
#include <math.h>

#define TOK 4096
#define DM  512
#define HF  2048
#define NE  8

typedef __bf16 bf16x8 __attribute__((ext_vector_type(8)));
typedef float  floatx16 __attribute__((ext_vector_type(16)));

// float -> bf16 (round-to-nearest-even), raw ushort bits
__device__ __forceinline__ unsigned short f2b(float f) {
    union { float f; unsigned u; } v; v.f = f;
    return (unsigned short)((v.u + 0x7fffu + ((v.u >> 16) & 1u)) >> 16);
}

// async global->LDS, 16 bytes per lane (dest = wave-uniform base + lane*16,
// global source address is PER-LANE -> used for perm-indirect A gather in fc1)
__device__ __forceinline__ void load_lds16(const void* g, void* l) {
    __builtin_amdgcn_global_load_lds(
        (__attribute__((address_space(1))) unsigned int*)g,
        (__attribute__((address_space(3))) unsigned int*)l, 16, 0, 0);
}

// 64x64 fp32->bf16 transpose tile; tile buffer passed in so callers can
// OVERLAY it on other LDS (disjoint lifetime) instead of paying additive LDS.
template <int NTHR>
__device__ __forceinline__ void transpose_tile(unsigned short (*tile)[68],
                                               const float* __restrict__ src,
                                               unsigned short* __restrict__ dst,
                                               int K, int N, int k0, int n0) {
#pragma unroll
    for (int i = 0; i < 1024 / NTHR; i++) {
        int it = threadIdx.x + i * NTHR;
        int r = it >> 4, tc = it & 15;
        const float4 v = *(const float4*)(src + (size_t)(k0 + r) * N + n0 + tc * 4);
        tile[r][tc * 4 + 0] = f2b(v.x);
        tile[r][tc * 4 + 1] = f2b(v.y);
        tile[r][tc * 4 + 2] = f2b(v.z);
        tile[r][tc * 4 + 3] = f2b(v.w);
    }
    __syncthreads();
#pragma unroll
    for (int i = 0; i < 1024 / NTHR; i++) {
        int it = threadIdx.x + i * NTHR;
        int nrow = it >> 4, tc = it & 15;
        ushort4 o;
        o.x = tile[tc * 4 + 0][nrow];
        o.y = tile[tc * 4 + 1][nrow];
        o.z = tile[tc * 4 + 2][nrow];
        o.w = tile[tc * 4 + 3][nrow];
        *(ushort4*)(dst + (size_t)(n0 + nrow) * K + k0 + tc * 4) = o;
    }
}

// Fused: router (blocks 0..1023, one wave per token) + W1 transpose (2048 blocks,
// XCD-PINNED: transpose block for expert e has id%8==e).
// Router also emits xb = bf16(x) in TOKEN order.
__global__ __launch_bounds__(256)
void k_router_trW1(const float* __restrict__ x, const float* __restrict__ Wr,
                   const float* __restrict__ br, const float* __restrict__ W1,
                   int* __restrict__ routes, unsigned short* __restrict__ xb,
                   unsigned short* __restrict__ W1t) {
    if (blockIdx.x >= TOK / 4) {            // W1: [E][512][2048] -> [E][2048][512]
        __shared__ unsigned short tl[64][68];
        int bt = blockIdx.x - TOK / 4;      // 1024%8==0 -> id%8 == bt%8 == e
        int e = bt & 7, tile = bt >> 3;     // 8 k-tiles x 32 n-tiles
        transpose_tile<256>(tl, W1 + (size_t)e * DM * HF, W1t + (size_t)e * HF * DM,
                            DM, HF, (tile >> 5) * 64, (tile & 31) * 64);
        return;
    }
    int t = blockIdx.x * 4 + (threadIdx.x >> 6);
    int lane = threadIdx.x & 63;
    const float4* xr = (const float4*)(x + (size_t)t * DM);
    float4 v0 = xr[lane * 2 + 0];           // 8 consecutive d per lane
    float4 v1 = xr[lane * 2 + 1];
    float xv[8] = {v0.x, v0.y, v0.z, v0.w, v1.x, v1.y, v1.z, v1.w};

    union { unsigned short u[8]; int4 q; } pk;
#pragma unroll
    for (int k = 0; k < 8; k++) pk.u[k] = f2b(xv[k]);
    *(int4*)(xb + (size_t)t * DM + lane * 8) = pk.q;   // coalesced 16B/lane

    float acc[NE];
#pragma unroll
    for (int e = 0; e < NE; e++) acc[e] = 0.f;
#pragma unroll
    for (int k = 0; k < 8; k++) {
        const float* w = Wr + (size_t)(lane * 8 + k) * NE;
        float4 wa = *(const float4*)(w);
        float4 wb = *(const float4*)(w + 4);
        acc[0] += xv[k] * wa.x; acc[1] += xv[k] * wa.y;
        acc[2] += xv[k] * wa.z; acc[3] += xv[k] * wa.w;
        acc[4] += xv[k] * wb.x; acc[5] += xv[k] * wb.y;
        acc[6] += xv[k] * wb.z; acc[7] += xv[k] * wb.w;
    }
#pragma unroll
    for (int off = 32; off > 0; off >>= 1)
#pragma unroll
        for (int e = 0; e < NE; e++) acc[e] += __shfl_down(acc[e], off, 64);
    if (lane == 0) {
        int best = 0; float bv = acc[0] + br[0];
#pragma unroll
        for (int e = 1; e < NE; e++) {
            float v = acc[e] + br[e];
            if (v > bv) { bv = v; best = e; }   // strict > == first-max (jnp.argmax)
        }
        routes[t] = best;
    }
}

// Organize only (1 block): ballot-based histogram + prefix + perm, zero atomics.
__global__ __launch_bounds__(1024)
void k_organize(const int* __restrict__ routes, int* __restrict__ offsets,
                int* __restrict__ perm) {
    __shared__ int wcnt[16][NE], wbase[16][NE], off[NE + 1], tot[NE];
    int tid = threadIdx.x, lane = tid & 63, w = tid >> 6;
    int4 r4 = *(const int4*)&routes[tid * 4];
    int e_[4] = {r4.x, r4.y, r4.z, r4.w};
    unsigned long long below = (1ull << lane) - 1ull;
    int rank[4];
#pragma unroll
    for (int e = 0; e < NE; e++) {
        int c = 0;
#pragma unroll
        for (int j = 0; j < 4; j++) {
            unsigned long long m = __ballot(e_[j] == e);
            if (e_[j] == e) rank[j] = c + __popcll(m & below);
            c += __popcll(m);
        }
        if (lane == 0) wcnt[w][e] = c;
    }
    __syncthreads();
    if (tid < NE) {                          // prefix over waves, per expert
        int s = 0;
#pragma unroll
        for (int ww = 0; ww < 16; ww++) { wbase[ww][tid] = s; s += wcnt[ww][tid]; }
        tot[tid] = s;
    }
    __syncthreads();
    if (tid == 0) {
        int s = 0;
#pragma unroll
        for (int e = 0; e < NE; e++) { off[e] = s; s += tot[e]; }
        off[NE] = s;
    }
    __syncthreads();
#pragma unroll
    for (int j = 0; j < 4; j++) {
        int e = e_[j];
        perm[off[e] + wbase[w][e] + rank[j]] = tid * 4 + j;
    }
    if (tid < NE + 1) offsets[tid] = off[tid];
}

// Grouped GEMM: 64x128 block, 4 waves (2Mx2N) of 32x64, dbuf LDS, XOR bank
// swizzle, plain __syncthreads protocol, expert->XCD 1D grid (id%8==e).
// Round-10 single change vs the 81.6-us round-6 base: BK=64 (8 K-iters, was
// 16). Model: each iteration's __syncthreads (implicit vmcnt(0)) serializes
// on the prefetch latency (~1-2k cyc) regardless of occupancy (r5/r6: occ
// 22->41% moved duration <6%). Halving the barrier count halves that serial
// wall. LDS 48 KB (2 bufs x (A 64x64 + B 128x64) bf16) -> 3 blocks/CU.
// Swizzle at 128-B rows: phys chunk pc of row holds global chunk pc^(row&7)
// (proven bit-exact in round-1's BK=64 run). Same ascending k order ->
// bit-identical accumulation vs BK=32.
// FC1: A perm-indirect gather from token-order xb; epilogue GELU -> hg;
//      ids >= NE*XT*YT carry the W2 transpose (2048 tiles, id%8==e2 pinned).
// FC2 (KSPLIT=4): K-slice partials -> pbuf[ks]; k_reduce sums + bias + scatter.
template <int KD, int ND, bool FC1, int KSPLIT, int XT, int YT>
__global__ __launch_bounds__(256)
void k_gemm(const unsigned short* __restrict__ A,
            const unsigned short* __restrict__ Bt,
            const float* __restrict__ bias,
            unsigned short* __restrict__ hg,
            float* __restrict__ pbuf,
            const int* __restrict__ offsets,
            const int* __restrict__ perm,
            const float* __restrict__ W2s,
            unsigned short* __restrict__ W2d) {
    __shared__ unsigned short smem[2 * 12288];   // 2 bufs x (A 4096 + B 8192) ushorts = 48 KB

    const int id = blockIdx.x;
    if constexpr (FC1) {
        if (id >= NE * XT * YT) {           // W2: [E][2048][512] -> [E][512][2048]
            int bt = id - NE * XT * YT;     // 0..2047; 2048%8==0 -> id%8 == bt%8
            int e2 = bt & 7, tl = bt >> 3;  // pin: W2t expert panel -> XCD e2
            transpose_tile<256>((unsigned short(*)[68])smem,   // LDS overlay
                                W2s + (size_t)e2 * HF * DM, W2d + (size_t)e2 * DM * HF,
                                HF, DM, (tl >> 3) * 64, (tl & 7) * 64);
            return;
        }
    }
    const int e  = id & 7;                  // id%8 == e -> expert-private XCD
    int t = id >> 3;
    const int ks = t % KSPLIT; t /= KSPLIT;
    const int bx = t % XT;
    const int by = t / XT;

    const int seg0 = offsets[e];
    const int cnt  = offsets[e + 1] - seg0;
    const int m0 = by * 64;
    if (m0 >= cnt) return;
    const int n0 = bx * 128;

    const unsigned short* Bexp = Bt + (size_t)e * ND * KD;

    const int tid  = threadIdx.x;
    const int lane = tid & 63;
    const int wave = tid >> 6;
    const int wm = (wave >> 1) * 32;   // wave M offset in 64-row block tile
    const int wn = (wave & 1) * 64;    // wave N offset in 128-col block tile

    // staging sources, hoisted (k-invariant). 128-B rows: phys slot
    // (row = fo>>7, pc = (fo>>4)&7) holds global chunk c = pc ^ (row&7).
    const unsigned short* aSrc[2];     // A tile 64x64 = 8 KB -> 2 chunks/thread
    const unsigned short* bSrc[4];     // B tile 128x64 = 16 KB -> 4 chunks/thread
    int foA[2], foB[4];
#pragma unroll
    for (int r = 0; r < 2; r++) {
        int fo  = tid * 16 + r * 4096;
        int row = fo >> 7;
        int c   = ((fo >> 4) & 7) ^ (row & 7);
        foA[r] = fo;
        if constexpr (FC1) {
            int idx = seg0 + m0 + row;             // clamp: tail rows never stored
            if (idx > TOK - 1) idx = TOK - 1;
            aSrc[r] = A + (size_t)perm[idx] * KD + c * 8;   // token-order xb
        } else {
            aSrc[r] = A + (size_t)(seg0 + m0 + row) * KD + c * 8;  // grouped hg
        }
    }
#pragma unroll
    for (int r = 0; r < 4; r++) {
        int fo  = tid * 16 + r * 4096;
        int row = fo >> 7;
        int c   = ((fo >> 4) & 7) ^ (row & 7);
        foB[r] = fo;
        bSrc[r] = Bexp + (size_t)(n0 + row) * KD + c * 8;
    }
    auto stage = [&](int k0, int buf) {
        char* ab = (char*)(smem + buf * 12288);          // A: 8 KB
        char* bb = (char*)(smem + buf * 12288 + 4096);   // B: 16 KB (ushort ofs 4096)
#pragma unroll
        for (int r = 0; r < 2; r++) load_lds16(aSrc[r] + k0, ab + foA[r]);
#pragma unroll
        for (int r = 0; r < 4; r++) load_lds16(bSrc[r] + k0, bb + foB[r]);
    };

    // fragment read addressing (32x32x16: m/n = lane&31, k = (lane>>5)*8 + j)
    const int fr = lane & 31;
    const int hi = lane >> 5;
    const int s8 = fr & 7;              // (row&7): wm/wn are multiples of 8
    int sw[4];
#pragma unroll
    for (int kk = 0; kk < 4; kk++) sw[kk] = (((kk << 1) | hi) ^ s8) * 8;
    const int aBase = (wm + fr) * 64;
    const int bBase = (wn + fr) * 64;

    floatx16 acc[2];
#pragma unroll
    for (int j = 0; j < 2; j++)
#pragma unroll
        for (int r = 0; r < 16; r++) acc[j][r] = 0.f;

    const int kBase = ks * (KD / KSPLIT);
    const int kEnd  = kBase + (KD / KSPLIT);
    stage(kBase, 0);
    int cur = 0;
    for (int k0 = kBase; k0 < kEnd; k0 += 64) {
        __syncthreads();   // buf `cur` staged; prior reads of cur^1 done
        if (k0 + 64 < kEnd) stage(k0 + 64, cur ^ 1);   // prefetch overlaps MFMA
        const unsigned short* Ab = smem + cur * 12288;
        const unsigned short* Bb = smem + cur * 12288 + 4096;
#pragma unroll
        for (int kk = 0; kk < 4; kk++) {
            bf16x8 af = *(const bf16x8*)&Ab[aBase + sw[kk]];
            bf16x8 bf[2];
#pragma unroll
            for (int j = 0; j < 2; j++)
                bf[j] = *(const bf16x8*)&Bb[bBase + j * 2048 + sw[kk]];
#pragma unroll
            for (int j = 0; j < 2; j++)
                acc[j] = __builtin_amdgcn_mfma_f32_32x32x16_bf16(af, bf[j], acc[j], 0, 0, 0);
        }
        cur ^= 1;
    }

    // epilogue: 32x32 C/D layout col=lane&31, row=(reg&3)+8*(reg>>2)+4*(lane>>5)
    const int rbase = 4 * hi;
#pragma unroll
    for (int j = 0; j < 2; j++) {
        int col = n0 + wn + j * 32 + fr;
        float bv = FC1 ? bias[(size_t)e * ND + col] : 0.f;
#pragma unroll
        for (int r = 0; r < 16; r++) {
            int grow = m0 + wm + rbase + (r & 3) + 8 * (r >> 2);
            if (grow < cnt) {
                float v = acc[j][r] + bv;
                if constexpr (FC1) {
                    v = 0.5f * v * (1.0f + erff(v * 0.70710678118654752f)); // exact GELU
                    hg[(size_t)(seg0 + grow) * ND + col] = f2b(v);
                } else {
                    pbuf[((size_t)ks * TOK + seg0 + grow) * ND + col] = v;
                }
            }
        }
    }
}

// out[perm[g]][:] = sum_ks pbuf[ks][g][:] + b2[e(g)][:]
__global__ __launch_bounds__(128)
void k_reduce(const float* __restrict__ pbuf, const int* __restrict__ perm,
              const int* __restrict__ offsets, const float* __restrict__ b2,
              float* __restrict__ out) {
    int g = blockIdx.x;
    int tok = perm[g];
    int e = 0;
#pragma unroll
    for (int i = 1; i < NE; i++) e += (g >= offsets[i]);
    int c = threadIdx.x * 4;
    float4 o = *(const float4*)&b2[(size_t)e * DM + c];
#pragma unroll
    for (int ks = 0; ks < 4; ks++) {
        float4 a = *(const float4*)&pbuf[((size_t)ks * TOK + g) * DM + c];
        o.x += a.x; o.y += a.y; o.z += a.z; o.w += a.w;
    }
    *(float4*)&out[(size_t)tok * DM + c] = o;
}

extern "C" void kernel_launch(void* const* d_in, const int* in_sizes, int n_in,
                              void* d_out, int out_size, void* d_ws, size_t ws_size,
                              hipStream_t stream) {
    const float* x  = (const float*)d_in[0];
    const float* Wr = (const float*)d_in[1];
    const float* br = (const float*)d_in[2];
    const float* W1 = (const float*)d_in[3];
    const float* b1 = (const float*)d_in[4];
    const float* W2 = (const float*)d_in[5];
    const float* b2 = (const float*)d_in[6];
    float* out = (float*)d_out;

    char* ws = (char*)d_ws;
    int* routes  = (int*)ws;            // [4096]
    int* perm    = routes + TOK;        // [4096]
    int* offsets = perm + TOK;          // [9]
    unsigned short* xb  = (unsigned short*)(ws + 65536);     // [4096][512]  bf16 token-order (4 MB)
    unsigned short* hg  = xb + (size_t)TOK * DM;             // [4096][2048] bf16 grouped (16 MB)
    unsigned short* W1t = hg + (size_t)TOK * HF;             // [E][HF][DM]  bf16 (16.8 MB)
    unsigned short* W2t = W1t + (size_t)NE * HF * DM;        // [E][DM][HF]  bf16 (16.8 MB)
    float* pbuf = (float*)(W2t + (size_t)NE * DM * HF);      // [4][4096][512] fp32 (33.5 MB)
    // FC2 A-tile overruns past hg end land in W1t (valid memory, non-NaN bf16);
    // rows >= cnt never stored. FC1 A rows are perm-clamped (no overrun).
    // YT=16 with 64-row tiles covers cnt up to 1024 (>20 sigma above 512 mean).

    // 1: router (+ token-order bf16 x) || W1 transpose (XCD-pinned writers)
    k_router_trW1<<<TOK / 4 + 2048, 256, 0, stream>>>(x, Wr, br, W1, routes, xb, W1t);
    // 2: ballot organize (1 block, ~2 us)
    k_organize<<<1, 1024, 0, stream>>>(routes, offsets, perm);
    // 3: fc1 (perm-gather in A staging), 64x128 tiles BK=64, expert->XCD grid:
    //    ids 0..2047 GEMM (16x * 16y per expert), ids 2048..4095 W2 transpose
    k_gemm<DM, HF, true, 1, 16, 16><<<NE * 256 + 2048, 256, 0, stream>>>(
        xb, W1t, b1, hg, nullptr, offsets, perm, W2, W2t);
    // 4: fc2, split-K=4, 64x128 tiles BK=64, expert->XCD grid (4x * 16y * 4ks)
    k_gemm<HF, DM, false, 4, 4, 16><<<NE * 256, 256, 0, stream>>>(
        hg, W2t, nullptr, nullptr, pbuf, offsets, perm, nullptr, nullptr);
    // 5: reduce + bias + scatter
    k_reduce<<<TOK, 128, 0, stream>>>(pbuf, perm, offsets, b2, out);
}

// Round 12
// 86.730 us; speedup vs baseline: 1.1150x; 1.0024x over previous
//
#include <hip/hip_runtime.h>
#include <math.h>

#define TOK 4096
#define DM  512
#define HF  2048
#define NE  8

typedef __bf16 bf16x8 __attribute__((ext_vector_type(8)));
typedef float  floatx16 __attribute__((ext_vector_type(16)));

// float -> bf16 (round-to-nearest-even), raw ushort bits
__device__ __forceinline__ unsigned short f2b(float f) {
    union { float f; unsigned u; } v; v.f = f;
    return (unsigned short)((v.u + 0x7fffu + ((v.u >> 16) & 1u)) >> 16);
}

// async global->LDS, 16 bytes per lane (dest = wave-uniform base + lane*16,
// global source address is PER-LANE -> used for perm-indirect A gather in fc1)
__device__ __forceinline__ void load_lds16(const void* g, void* l) {
    __builtin_amdgcn_global_load_lds(
        (__attribute__((address_space(1))) unsigned int*)g,
        (__attribute__((address_space(3))) unsigned int*)l, 16, 0, 0);
}

// 64x64 fp32->bf16 transpose tile; tile buffer passed in so callers can
// OVERLAY it on other LDS (disjoint lifetime) instead of paying additive LDS.
template <int NTHR>
__device__ __forceinline__ void transpose_tile(unsigned short (*tile)[68],
                                               const float* __restrict__ src,
                                               unsigned short* __restrict__ dst,
                                               int K, int N, int k0, int n0) {
#pragma unroll
    for (int i = 0; i < 1024 / NTHR; i++) {
        int it = threadIdx.x + i * NTHR;
        int r = it >> 4, tc = it & 15;
        const float4 v = *(const float4*)(src + (size_t)(k0 + r) * N + n0 + tc * 4);
        tile[r][tc * 4 + 0] = f2b(v.x);
        tile[r][tc * 4 + 1] = f2b(v.y);
        tile[r][tc * 4 + 2] = f2b(v.z);
        tile[r][tc * 4 + 3] = f2b(v.w);
    }
    __syncthreads();
#pragma unroll
    for (int i = 0; i < 1024 / NTHR; i++) {
        int it = threadIdx.x + i * NTHR;
        int nrow = it >> 4, tc = it & 15;
        ushort4 o;
        o.x = tile[tc * 4 + 0][nrow];
        o.y = tile[tc * 4 + 1][nrow];
        o.z = tile[tc * 4 + 2][nrow];
        o.w = tile[tc * 4 + 3][nrow];
        *(ushort4*)(dst + (size_t)(n0 + nrow) * K + k0 + tc * 4) = o;
    }
}

// Fused: router (blocks 0..1023, one wave per token) + W1 transpose (2048 blocks,
// XCD-PINNED: transpose block for expert e has id%8==e).
// Router also emits xb = bf16(x) in TOKEN order.
__global__ __launch_bounds__(256)
void k_router_trW1(const float* __restrict__ x, const float* __restrict__ Wr,
                   const float* __restrict__ br, const float* __restrict__ W1,
                   int* __restrict__ routes, unsigned short* __restrict__ xb,
                   unsigned short* __restrict__ W1t) {
    if (blockIdx.x >= TOK / 4) {            // W1: [E][512][2048] -> [E][2048][512]
        __shared__ unsigned short tl[64][68];
        int bt = blockIdx.x - TOK / 4;      // 1024%8==0 -> id%8 == bt%8 == e
        int e = bt & 7, tile = bt >> 3;     // 8 k-tiles x 32 n-tiles
        transpose_tile<256>(tl, W1 + (size_t)e * DM * HF, W1t + (size_t)e * HF * DM,
                            DM, HF, (tile >> 5) * 64, (tile & 31) * 64);
        return;
    }
    int t = blockIdx.x * 4 + (threadIdx.x >> 6);
    int lane = threadIdx.x & 63;
    const float4* xr = (const float4*)(x + (size_t)t * DM);
    float4 v0 = xr[lane * 2 + 0];           // 8 consecutive d per lane
    float4 v1 = xr[lane * 2 + 1];
    float xv[8] = {v0.x, v0.y, v0.z, v0.w, v1.x, v1.y, v1.z, v1.w};

    union { unsigned short u[8]; int4 q; } pk;
#pragma unroll
    for (int k = 0; k < 8; k++) pk.u[k] = f2b(xv[k]);
    *(int4*)(xb + (size_t)t * DM + lane * 8) = pk.q;   // coalesced 16B/lane

    float acc[NE];
#pragma unroll
    for (int e = 0; e < NE; e++) acc[e] = 0.f;
#pragma unroll
    for (int k = 0; k < 8; k++) {
        const float* w = Wr + (size_t)(lane * 8 + k) * NE;
        float4 wa = *(const float4*)(w);
        float4 wb = *(const float4*)(w + 4);
        acc[0] += xv[k] * wa.x; acc[1] += xv[k] * wa.y;
        acc[2] += xv[k] * wa.z; acc[3] += xv[k] * wa.w;
        acc[4] += xv[k] * wb.x; acc[5] += xv[k] * wb.y;
        acc[6] += xv[k] * wb.z; acc[7] += xv[k] * wb.w;
    }
#pragma unroll
    for (int off = 32; off > 0; off >>= 1)
#pragma unroll
        for (int e = 0; e < NE; e++) acc[e] += __shfl_down(acc[e], off, 64);
    if (lane == 0) {
        int best = 0; float bv = acc[0] + br[0];
#pragma unroll
        for (int e = 1; e < NE; e++) {
            float v = acc[e] + br[e];
            if (v > bv) { bv = v; best = e; }   // strict > == first-max (jnp.argmax)
        }
        routes[t] = best;
    }
}

// Organize only (1 block): ballot-based histogram + prefix + perm, zero atomics.
__global__ __launch_bounds__(1024)
void k_organize(const int* __restrict__ routes, int* __restrict__ offsets,
                int* __restrict__ perm) {
    __shared__ int wcnt[16][NE], wbase[16][NE], off[NE + 1], tot[NE];
    int tid = threadIdx.x, lane = tid & 63, w = tid >> 6;
    int4 r4 = *(const int4*)&routes[tid * 4];
    int e_[4] = {r4.x, r4.y, r4.z, r4.w};
    unsigned long long below = (1ull << lane) - 1ull;
    int rank[4];
#pragma unroll
    for (int e = 0; e < NE; e++) {
        int c = 0;
#pragma unroll
        for (int j = 0; j < 4; j++) {
            unsigned long long m = __ballot(e_[j] == e);
            if (e_[j] == e) rank[j] = c + __popcll(m & below);
            c += __popcll(m);
        }
        if (lane == 0) wcnt[w][e] = c;
    }
    __syncthreads();
    if (tid < NE) {                          // prefix over waves, per expert
        int s = 0;
#pragma unroll
        for (int ww = 0; ww < 16; ww++) { wbase[ww][tid] = s; s += wcnt[ww][tid]; }
        tot[tid] = s;
    }
    __syncthreads();
    if (tid == 0) {
        int s = 0;
#pragma unroll
        for (int e = 0; e < NE; e++) { off[e] = s; s += tot[e]; }
        off[NE] = s;
    }
    __syncthreads();
#pragma unroll
    for (int j = 0; j < 4; j++) {
        int e = e_[j];
        perm[off[e] + wbase[w][e] + rank[j]] = tid * 4 + j;
    }
    if (tid < NE + 1) offsets[tid] = off[tid];
}

// Grouped GEMM: 64x128 block, 4 waves (2Mx2N) of 32x64, BK=32, XOR bank
// swizzle, expert->XCD 1D grid (id%8==e) — the proven round-6 base.
// Round-12 single change: RING-3 LDS + COUNTED VMCNT instead of the dbuf
// __syncthreads protocol. Mechanism (fits all r5/r6/r10 data): __syncthreads
// drains vmcnt(0), so each iteration waited on the prefetch issued ONE
// MFMA-phase (~100-200 cyc) earlier — a 200-900 cyc load latency stalls
// every iteration; barrier count (r10) and occupancy (r5/r6) were both null
// because the stall is latency-chain-internal. Now: per iter,
//   s_waitcnt vmcnt(3)   — wait ONLY this wave's tile-t loads (t+1 in flight)
//   s_barrier            — all waves pre-waited => tile t fully in LDS
//   stage(t+2, (t+2)%3)  — safe: barrier proves all waves done reading it
//   MFMA on buf t%3
// Prefetch now has TWO compute phases (~400-500 cyc) to land. No
// sched_barrier / setprio (r2's confound, m141 trap). Bit-identical math.
// FC1: A perm-indirect gather from token-order xb; epilogue GELU -> hg;
//      ids >= NE*XT*YT carry the W2 transpose (2048 tiles, id%8==e2 pinned).
// FC2 (KSPLIT=4): K-slice partials -> pbuf[ks]; k_reduce sums + bias + scatter.
template <int KD, int ND, bool FC1, int KSPLIT, int XT, int YT>
__global__ __launch_bounds__(256)
void k_gemm(const unsigned short* __restrict__ A,
            const unsigned short* __restrict__ Bt,
            const float* __restrict__ bias,
            unsigned short* __restrict__ hg,
            float* __restrict__ pbuf,
            const int* __restrict__ offsets,
            const int* __restrict__ perm,
            const float* __restrict__ W2s,
            unsigned short* __restrict__ W2d) {
    __shared__ unsigned short smem[3 * 6144];   // ring-3 x (A 64x32 + B 128x32) = 36 KB

    const int id = blockIdx.x;
    if constexpr (FC1) {
        if (id >= NE * XT * YT) {           // W2: [E][2048][512] -> [E][512][2048]
            int bt = id - NE * XT * YT;     // 0..2047; 2048%8==0 -> id%8 == bt%8
            int e2 = bt & 7, tl = bt >> 3;  // pin: W2t expert panel -> XCD e2
            transpose_tile<256>((unsigned short(*)[68])smem,   // LDS overlay
                                W2s + (size_t)e2 * HF * DM, W2d + (size_t)e2 * DM * HF,
                                HF, DM, (tl >> 3) * 64, (tl & 7) * 64);
            return;
        }
    }
    const int e  = id & 7;                  // id%8 == e -> expert-private XCD
    int t = id >> 3;
    const int ks = t % KSPLIT; t /= KSPLIT;
    const int bx = t % XT;
    const int by = t / XT;

    const int seg0 = offsets[e];
    const int cnt  = offsets[e + 1] - seg0;
    const int m0 = by * 64;
    if (m0 >= cnt) return;
    const int n0 = bx * 128;

    const unsigned short* Bexp = Bt + (size_t)e * ND * KD;

    const int tid  = threadIdx.x;
    const int lane = tid & 63;
    const int wave = tid >> 6;
    const int wm = (wave >> 1) * 32;   // wave M offset in 64-row block tile
    const int wn = (wave & 1) * 64;    // wave N offset in 128-col block tile

    // staging sources, hoisted (k-invariant). phys slot (row = fo>>6,
    // pc = (fo>>4)&3) holds global chunk c = pc ^ ((row>>1)&3).
    const unsigned short* aSrc;        // A tile 64x32 = 4 KB -> 1 chunk/thread
    const unsigned short* bSrc[2];     // B tile 128x32 = 8 KB -> 2 chunks/thread
    const int foA = tid * 16;
    {
        int row = foA >> 6;
        int c   = ((foA >> 4) & 3) ^ ((row >> 1) & 3);
        if constexpr (FC1) {
            int idx = seg0 + m0 + row;             // clamp: tail rows never stored
            if (idx > TOK - 1) idx = TOK - 1;
            aSrc = A + (size_t)perm[idx] * KD + c * 8;   // token-order xb
        } else {
            aSrc = A + (size_t)(seg0 + m0 + row) * KD + c * 8;  // grouped hg
        }
    }
    int foB[2];
#pragma unroll
    for (int r = 0; r < 2; r++) {
        int fo  = tid * 16 + r * 4096;
        int row = fo >> 6;
        int c   = ((fo >> 4) & 3) ^ ((row >> 1) & 3);
        foB[r] = fo;
        bSrc[r] = Bexp + (size_t)(n0 + row) * KD + c * 8;
    }
    auto stage = [&](int k0, int buf) {     // 3 vm-ops per thread per tile
        char* ab = (char*)(smem + buf * 6144);
        char* bb = (char*)(smem + buf * 6144 + 2048);
        load_lds16(aSrc + k0, ab + foA);
#pragma unroll
        for (int r = 0; r < 2; r++) load_lds16(bSrc[r] + k0, bb + foB[r]);
    };

    // fragment read addressing (32x32x16: m/n = lane&31, k = (lane>>5)*8 + j)
    const int fr = lane & 31;
    const int hi = lane >> 5;
    const int q  = (lane >> 1) & 3;
    const int sw[2] = { ((0 + hi) ^ q) * 8, ((2 + hi) ^ q) * 8 };
    const int aBase = (wm + fr) * 32;
    const int bBase = (wn + fr) * 32;

    floatx16 acc[2];
#pragma unroll
    for (int j = 0; j < 2; j++)
#pragma unroll
        for (int r = 0; r < 16; r++) acc[j][r] = 0.f;

    constexpr int NT = (KD / KSPLIT) / 32;     // 16 K-tiles for both GEMMs
    const int kBase = ks * (KD / KSPLIT);
    stage(kBase, 0);
    stage(kBase + 32, 1);
    for (int tt = 0; tt < NT; ++tt) {
        // wait this wave's tile-tt loads (3); leave tile-(tt+1)'s 3 in flight
        if (tt < NT - 1) asm volatile("s_waitcnt vmcnt(3)" ::: "memory");
        else             asm volatile("s_waitcnt vmcnt(0)" ::: "memory");
        __builtin_amdgcn_s_barrier();   // every wave pre-waited => tile tt in LDS
        if (tt + 2 < NT) stage(kBase + (tt + 2) * 32, (tt + 2) % 3);
        const unsigned short* Ab = smem + (tt % 3) * 6144;
        const unsigned short* Bb = Ab + 2048;
#pragma unroll
        for (int kk = 0; kk < 2; kk++) {
            bf16x8 af = *(const bf16x8*)&Ab[aBase + sw[kk]];
            bf16x8 bf[2];
#pragma unroll
            for (int j = 0; j < 2; j++)
                bf[j] = *(const bf16x8*)&Bb[bBase + j * 1024 + sw[kk]];
#pragma unroll
            for (int j = 0; j < 2; j++)
                acc[j] = __builtin_amdgcn_mfma_f32_32x32x16_bf16(af, bf[j], acc[j], 0, 0, 0);
        }
    }

    // epilogue: 32x32 C/D layout col=lane&31, row=(reg&3)+8*(reg>>2)+4*(lane>>5)
    const int rbase = 4 * hi;
#pragma unroll
    for (int j = 0; j < 2; j++) {
        int col = n0 + wn + j * 32 + fr;
        float bv = FC1 ? bias[(size_t)e * ND + col] : 0.f;
#pragma unroll
        for (int r = 0; r < 16; r++) {
            int grow = m0 + wm + rbase + (r & 3) + 8 * (r >> 2);
            if (grow < cnt) {
                float v = acc[j][r] + bv;
                if constexpr (FC1) {
                    v = 0.5f * v * (1.0f + erff(v * 0.70710678118654752f)); // exact GELU
                    hg[(size_t)(seg0 + grow) * ND + col] = f2b(v);
                } else {
                    pbuf[((size_t)ks * TOK + seg0 + grow) * ND + col] = v;
                }
            }
        }
    }
}

// out[perm[g]][:] = sum_ks pbuf[ks][g][:] + b2[e(g)][:]
__global__ __launch_bounds__(128)
void k_reduce(const float* __restrict__ pbuf, const int* __restrict__ perm,
              const int* __restrict__ offsets, const float* __restrict__ b2,
              float* __restrict__ out) {
    int g = blockIdx.x;
    int tok = perm[g];
    int e = 0;
#pragma unroll
    for (int i = 1; i < NE; i++) e += (g >= offsets[i]);
    int c = threadIdx.x * 4;
    float4 o = *(const float4*)&b2[(size_t)e * DM + c];
#pragma unroll
    for (int ks = 0; ks < 4; ks++) {
        float4 a = *(const float4*)&pbuf[((size_t)ks * TOK + g) * DM + c];
        o.x += a.x; o.y += a.y; o.z += a.z; o.w += a.w;
    }
    *(float4*)&out[(size_t)tok * DM + c] = o;
}

extern "C" void kernel_launch(void* const* d_in, const int* in_sizes, int n_in,
                              void* d_out, int out_size, void* d_ws, size_t ws_size,
                              hipStream_t stream) {
    const float* x  = (const float*)d_in[0];
    const float* Wr = (const float*)d_in[1];
    const float* br = (const float*)d_in[2];
    const float* W1 = (const float*)d_in[3];
    const float* b1 = (const float*)d_in[4];
    const float* W2 = (const float*)d_in[5];
    const float* b2 = (const float*)d_in[6];
    float* out = (float*)d_out;

    char* ws = (char*)d_ws;
    int* routes  = (int*)ws;            // [4096]
    int* perm    = routes + TOK;        // [4096]
    int* offsets = perm + TOK;          // [9]
    unsigned short* xb  = (unsigned short*)(ws + 65536);     // [4096][512]  bf16 token-order (4 MB)
    unsigned short* hg  = xb + (size_t)TOK * DM;             // [4096][2048] bf16 grouped (16 MB)
    unsigned short* W1t = hg + (size_t)TOK * HF;             // [E][HF][DM]  bf16 (16.8 MB)
    unsigned short* W2t = W1t + (size_t)NE * HF * DM;        // [E][DM][HF]  bf16 (16.8 MB)
    float* pbuf = (float*)(W2t + (size_t)NE * DM * HF);      // [4][4096][512] fp32 (33.5 MB)
    // FC2 A-tile overruns past hg end land in W1t (valid memory, non-NaN bf16);
    // rows >= cnt never stored. FC1 A rows are perm-clamped (no overrun).
    // YT=16 with 64-row tiles covers cnt up to 1024 (>20 sigma above 512 mean).

    // 1: router (+ token-order bf16 x) || W1 transpose (XCD-pinned writers)
    k_router_trW1<<<TOK / 4 + 2048, 256, 0, stream>>>(x, Wr, br, W1, routes, xb, W1t);
    // 2: ballot organize (1 block, ~2 us)
    k_organize<<<1, 1024, 0, stream>>>(routes, offsets, perm);
    // 3: fc1 (perm-gather in A staging), 64x128 tiles, expert->XCD grid:
    //    ids 0..2047 GEMM (16x * 16y per expert), ids 2048..4095 W2 transpose
    k_gemm<DM, HF, true, 1, 16, 16><<<NE * 256 + 2048, 256, 0, stream>>>(
        xb, W1t, b1, hg, nullptr, offsets, perm, W2, W2t);
    // 4: fc2, split-K=4, 64x128 tiles, expert->XCD grid (4x * 16y * 4ks)
    k_gemm<HF, DM, false, 4, 4, 16><<<NE * 256, 256, 0, stream>>>(
        hg, W2t, nullptr, nullptr, pbuf, offsets, perm, nullptr, nullptr);
    // 5: reduce + bias + scatter
    k_reduce<<<TOK, 128, 0, stream>>>(pbuf, perm, offsets, b2, out);
}

// Round 13
// 79.383 us; speedup vs baseline: 1.2181x; 1.0925x over previous
//
#include <hip/hip_runtime.h>
#include <math.h>

#define TOK 4096
#define DM  512
#define HF  2048
#define NE  8

typedef __bf16 bf16x8 __attribute__((ext_vector_type(8)));
typedef float  floatx16 __attribute__((ext_vector_type(16)));

// float -> bf16 (round-to-nearest-even), raw ushort bits
__device__ __forceinline__ unsigned short f2b(float f) {
    union { float f; unsigned u; } v; v.f = f;
    return (unsigned short)((v.u + 0x7fffu + ((v.u >> 16) & 1u)) >> 16);
}

// async global->LDS, 16 bytes per lane (dest = wave-uniform base + lane*16,
// global source address is PER-LANE -> used for perm-indirect A gather in fc1)
__device__ __forceinline__ void load_lds16(const void* g, void* l) {
    __builtin_amdgcn_global_load_lds(
        (__attribute__((address_space(1))) unsigned int*)g,
        (__attribute__((address_space(3))) unsigned int*)l, 16, 0, 0);
}

// 64x64 fp32->bf16 transpose tile; tile buffer passed in so callers can
// OVERLAY it on other LDS (disjoint lifetime) instead of paying additive LDS.
template <int NTHR>
__device__ __forceinline__ void transpose_tile(unsigned short (*tile)[68],
                                               const float* __restrict__ src,
                                               unsigned short* __restrict__ dst,
                                               int K, int N, int k0, int n0) {
#pragma unroll
    for (int i = 0; i < 1024 / NTHR; i++) {
        int it = threadIdx.x + i * NTHR;
        int r = it >> 4, tc = it & 15;
        const float4 v = *(const float4*)(src + (size_t)(k0 + r) * N + n0 + tc * 4);
        tile[r][tc * 4 + 0] = f2b(v.x);
        tile[r][tc * 4 + 1] = f2b(v.y);
        tile[r][tc * 4 + 2] = f2b(v.z);
        tile[r][tc * 4 + 3] = f2b(v.w);
    }
    __syncthreads();
#pragma unroll
    for (int i = 0; i < 1024 / NTHR; i++) {
        int it = threadIdx.x + i * NTHR;
        int nrow = it >> 4, tc = it & 15;
        ushort4 o;
        o.x = tile[tc * 4 + 0][nrow];
        o.y = tile[tc * 4 + 1][nrow];
        o.z = tile[tc * 4 + 2][nrow];
        o.w = tile[tc * 4 + 3][nrow];
        *(ushort4*)(dst + (size_t)(n0 + nrow) * K + k0 + tc * 4) = o;
    }
}

// Fused: router (blocks 0..1023, one wave per token) + W1 transpose (2048 blocks,
// XCD-PINNED: transpose block for expert e has id%8==e).
// Router also emits xb = bf16(x) in TOKEN order.
__global__ __launch_bounds__(256)
void k_router_trW1(const float* __restrict__ x, const float* __restrict__ Wr,
                   const float* __restrict__ br, const float* __restrict__ W1,
                   int* __restrict__ routes, unsigned short* __restrict__ xb,
                   unsigned short* __restrict__ W1t) {
    if (blockIdx.x >= TOK / 4) {            // W1: [E][512][2048] -> [E][2048][512]
        __shared__ unsigned short tl[64][68];
        int bt = blockIdx.x - TOK / 4;      // 1024%8==0 -> id%8 == bt%8 == e
        int e = bt & 7, tile = bt >> 3;     // 8 k-tiles x 32 n-tiles
        transpose_tile<256>(tl, W1 + (size_t)e * DM * HF, W1t + (size_t)e * HF * DM,
                            DM, HF, (tile >> 5) * 64, (tile & 31) * 64);
        return;
    }
    int t = blockIdx.x * 4 + (threadIdx.x >> 6);
    int lane = threadIdx.x & 63;
    const float4* xr = (const float4*)(x + (size_t)t * DM);
    float4 v0 = xr[lane * 2 + 0];           // 8 consecutive d per lane
    float4 v1 = xr[lane * 2 + 1];
    float xv[8] = {v0.x, v0.y, v0.z, v0.w, v1.x, v1.y, v1.z, v1.w};

    union { unsigned short u[8]; int4 q; } pk;
#pragma unroll
    for (int k = 0; k < 8; k++) pk.u[k] = f2b(xv[k]);
    *(int4*)(xb + (size_t)t * DM + lane * 8) = pk.q;   // coalesced 16B/lane

    float acc[NE];
#pragma unroll
    for (int e = 0; e < NE; e++) acc[e] = 0.f;
#pragma unroll
    for (int k = 0; k < 8; k++) {
        const float* w = Wr + (size_t)(lane * 8 + k) * NE;
        float4 wa = *(const float4*)(w);
        float4 wb = *(const float4*)(w + 4);
        acc[0] += xv[k] * wa.x; acc[1] += xv[k] * wa.y;
        acc[2] += xv[k] * wa.z; acc[3] += xv[k] * wa.w;
        acc[4] += xv[k] * wb.x; acc[5] += xv[k] * wb.y;
        acc[6] += xv[k] * wb.z; acc[7] += xv[k] * wb.w;
    }
#pragma unroll
    for (int off = 32; off > 0; off >>= 1)
#pragma unroll
        for (int e = 0; e < NE; e++) acc[e] += __shfl_down(acc[e], off, 64);
    if (lane == 0) {
        int best = 0; float bv = acc[0] + br[0];
#pragma unroll
        for (int e = 1; e < NE; e++) {
            float v = acc[e] + br[e];
            if (v > bv) { bv = v; best = e; }   // strict > == first-max (jnp.argmax)
        }
        routes[t] = best;
    }
}

// Organize only (1 block): ballot-based histogram + prefix + perm, zero atomics.
__global__ __launch_bounds__(1024)
void k_organize(const int* __restrict__ routes, int* __restrict__ offsets,
                int* __restrict__ perm) {
    __shared__ int wcnt[16][NE], wbase[16][NE], off[NE + 1], tot[NE];
    int tid = threadIdx.x, lane = tid & 63, w = tid >> 6;
    int4 r4 = *(const int4*)&routes[tid * 4];
    int e_[4] = {r4.x, r4.y, r4.z, r4.w};
    unsigned long long below = (1ull << lane) - 1ull;
    int rank[4];
#pragma unroll
    for (int e = 0; e < NE; e++) {
        int c = 0;
#pragma unroll
        for (int j = 0; j < 4; j++) {
            unsigned long long m = __ballot(e_[j] == e);
            if (e_[j] == e) rank[j] = c + __popcll(m & below);
            c += __popcll(m);
        }
        if (lane == 0) wcnt[w][e] = c;
    }
    __syncthreads();
    if (tid < NE) {                          // prefix over waves, per expert
        int s = 0;
#pragma unroll
        for (int ww = 0; ww < 16; ww++) { wbase[ww][tid] = s; s += wcnt[ww][tid]; }
        tot[tid] = s;
    }
    __syncthreads();
    if (tid == 0) {
        int s = 0;
#pragma unroll
        for (int e = 0; e < NE; e++) { off[e] = s; s += tot[e]; }
        off[NE] = s;
    }
    __syncthreads();
#pragma unroll
    for (int j = 0; j < 4; j++) {
        int e = e_[j];
        perm[off[e] + wbase[w][e] + rank[j]] = tid * 4 + j;
    }
    if (tid < NE + 1) offsets[tid] = off[tid];
}

// Grouped GEMM: 64x128 block, 4 waves (2Mx2N) of 32x64, BK=32, dbuf LDS 24 KB,
// XOR bank swizzle, plain __syncthreads protocol (round-6 base, session best:
// protocol variants (r2/r10/r12), BK=64 (r10), occupancy 2-5 blocks/CU
// (r5/r6), stride pad (r7) all measured null or regressive vs this).
// Expert->XCD locality: 1D grid, id%8 == e. FC1: perm-indirect A gather;
// epilogue GELU -> hg; ids >= NE*XT*YT carry the W2 transpose, pinned
// id%8 == e2 so W2t panels land in the consumer expert's XCD-L2.
// FC2: K-slice partials -> pbuf[ks]; k_reduce sums + bias + scatter.
// Round-13: FC2 KSPLIT 4->2 ALONE (r8 bundled it with nt-stores, confounded):
// halves pbuf round-trip traffic (33.5->16.8 MB) and k_reduce's work;
// iteration count 16->32 is established as a weak variable (r10).
template <int KD, int ND, bool FC1, int KSPLIT, int XT, int YT>
__global__ __launch_bounds__(256)
void k_gemm(const unsigned short* __restrict__ A,
            const unsigned short* __restrict__ Bt,
            const float* __restrict__ bias,
            unsigned short* __restrict__ hg,
            float* __restrict__ pbuf,
            const int* __restrict__ offsets,
            const int* __restrict__ perm,
            const float* __restrict__ W2s,
            unsigned short* __restrict__ W2d) {
    __shared__ unsigned short smem[12288];   // 2 bufs x (A 64x32 + B 128x32) = 24 KB

    const int id = blockIdx.x;
    if constexpr (FC1) {
        if (id >= NE * XT * YT) {           // W2: [E][2048][512] -> [E][512][2048]
            int bt = id - NE * XT * YT;     // 0..2047; 2048%8==0 -> id%8 == bt%8
            int e2 = bt & 7, tl = bt >> 3;  // pin: W2t expert panel -> XCD e2
            transpose_tile<256>((unsigned short(*)[68])smem,   // LDS overlay
                                W2s + (size_t)e2 * HF * DM, W2d + (size_t)e2 * DM * HF,
                                HF, DM, (tl >> 3) * 64, (tl & 7) * 64);
            return;
        }
    }
    const int e  = id & 7;                  // id%8 == e -> expert-private XCD
    int t = id >> 3;
    const int ks = t % KSPLIT; t /= KSPLIT;
    const int bx = t % XT;
    const int by = t / XT;

    const int seg0 = offsets[e];
    const int cnt  = offsets[e + 1] - seg0;
    const int m0 = by * 64;
    if (m0 >= cnt) return;
    const int n0 = bx * 128;

    const unsigned short* Bexp = Bt + (size_t)e * ND * KD;

    const int tid  = threadIdx.x;
    const int lane = tid & 63;
    const int wave = tid >> 6;
    const int wm = (wave >> 1) * 32;   // wave M offset in 64-row block tile
    const int wn = (wave & 1) * 64;    // wave N offset in 128-col block tile

    // staging sources, hoisted (k-invariant). phys slot (row = fo>>6,
    // pc = (fo>>4)&3) holds global chunk c = pc ^ ((row>>1)&3).
    const unsigned short* aSrc;        // A tile 64x32 = 4 KB -> 1 chunk/thread
    const unsigned short* bSrc[2];     // B tile 128x32 = 8 KB -> 2 chunks/thread
    const int foA = tid * 16;
    {
        int row = foA >> 6;
        int c   = ((foA >> 4) & 3) ^ ((row >> 1) & 3);
        if constexpr (FC1) {
            int idx = seg0 + m0 + row;             // clamp: tail rows never stored
            if (idx > TOK - 1) idx = TOK - 1;
            aSrc = A + (size_t)perm[idx] * KD + c * 8;   // token-order xb
        } else {
            aSrc = A + (size_t)(seg0 + m0 + row) * KD + c * 8;  // grouped hg
        }
    }
    int foB[2];
#pragma unroll
    for (int r = 0; r < 2; r++) {
        int fo  = tid * 16 + r * 4096;
        int row = fo >> 6;
        int c   = ((fo >> 4) & 3) ^ ((row >> 1) & 3);
        foB[r] = fo;
        bSrc[r] = Bexp + (size_t)(n0 + row) * KD + c * 8;
    }
    auto stage = [&](int k0, int buf) {
        char* ab = (char*)(smem + buf * 6144);
        char* bb = (char*)(smem + buf * 6144 + 2048);
        load_lds16(aSrc + k0, ab + foA);
#pragma unroll
        for (int r = 0; r < 2; r++) load_lds16(bSrc[r] + k0, bb + foB[r]);
    };

    // fragment read addressing (32x32x16: m/n = lane&31, k = (lane>>5)*8 + j)
    const int fr = lane & 31;
    const int hi = lane >> 5;
    const int q  = (lane >> 1) & 3;
    const int sw[2] = { ((0 + hi) ^ q) * 8, ((2 + hi) ^ q) * 8 };
    const int aBase = (wm + fr) * 32;
    const int bBase = (wn + fr) * 32;

    floatx16 acc[2];
#pragma unroll
    for (int j = 0; j < 2; j++)
#pragma unroll
        for (int r = 0; r < 16; r++) acc[j][r] = 0.f;

    const int kBase = ks * (KD / KSPLIT);
    const int kEnd  = kBase + (KD / KSPLIT);
    stage(kBase, 0);
    int cur = 0;
    for (int k0 = kBase; k0 < kEnd; k0 += 32) {
        __syncthreads();   // buf `cur` staged; prior reads of cur^1 done
        if (k0 + 32 < kEnd) stage(k0 + 32, cur ^ 1);   // prefetch overlaps MFMA
        const unsigned short* Ab = smem + cur * 6144;
        const unsigned short* Bb = smem + cur * 6144 + 2048;
#pragma unroll
        for (int kk = 0; kk < 2; kk++) {
            bf16x8 af = *(const bf16x8*)&Ab[aBase + sw[kk]];
            bf16x8 bf[2];
#pragma unroll
            for (int j = 0; j < 2; j++)
                bf[j] = *(const bf16x8*)&Bb[bBase + j * 1024 + sw[kk]];
#pragma unroll
            for (int j = 0; j < 2; j++)
                acc[j] = __builtin_amdgcn_mfma_f32_32x32x16_bf16(af, bf[j], acc[j], 0, 0, 0);
        }
        cur ^= 1;
    }

    // epilogue: 32x32 C/D layout col=lane&31, row=(reg&3)+8*(reg>>2)+4*(lane>>5)
    const int rbase = 4 * hi;
#pragma unroll
    for (int j = 0; j < 2; j++) {
        int col = n0 + wn + j * 32 + fr;
        float bv = FC1 ? bias[(size_t)e * ND + col] : 0.f;
#pragma unroll
        for (int r = 0; r < 16; r++) {
            int grow = m0 + wm + rbase + (r & 3) + 8 * (r >> 2);
            if (grow < cnt) {
                float v = acc[j][r] + bv;
                if constexpr (FC1) {
                    v = 0.5f * v * (1.0f + erff(v * 0.70710678118654752f)); // exact GELU
                    hg[(size_t)(seg0 + grow) * ND + col] = f2b(v);
                } else {
                    pbuf[((size_t)ks * TOK + seg0 + grow) * ND + col] = v;
                }
            }
        }
    }
}

// out[perm[g]][:] = sum_ks pbuf[ks][g][:] + b2[e(g)][:]   (KSPLIT=2)
__global__ __launch_bounds__(128)
void k_reduce(const float* __restrict__ pbuf, const int* __restrict__ perm,
              const int* __restrict__ offsets, const float* __restrict__ b2,
              float* __restrict__ out) {
    int g = blockIdx.x;
    int tok = perm[g];
    int e = 0;
#pragma unroll
    for (int i = 1; i < NE; i++) e += (g >= offsets[i]);
    int c = threadIdx.x * 4;
    float4 o = *(const float4*)&b2[(size_t)e * DM + c];
#pragma unroll
    for (int ks = 0; ks < 2; ks++) {
        float4 a = *(const float4*)&pbuf[((size_t)ks * TOK + g) * DM + c];
        o.x += a.x; o.y += a.y; o.z += a.z; o.w += a.w;
    }
    *(float4*)&out[(size_t)tok * DM + c] = o;
}

extern "C" void kernel_launch(void* const* d_in, const int* in_sizes, int n_in,
                              void* d_out, int out_size, void* d_ws, size_t ws_size,
                              hipStream_t stream) {
    const float* x  = (const float*)d_in[0];
    const float* Wr = (const float*)d_in[1];
    const float* br = (const float*)d_in[2];
    const float* W1 = (const float*)d_in[3];
    const float* b1 = (const float*)d_in[4];
    const float* W2 = (const float*)d_in[5];
    const float* b2 = (const float*)d_in[6];
    float* out = (float*)d_out;

    char* ws = (char*)d_ws;
    int* routes  = (int*)ws;            // [4096]
    int* perm    = routes + TOK;        // [4096]
    int* offsets = perm + TOK;          // [9]
    unsigned short* xb  = (unsigned short*)(ws + 65536);     // [4096][512]  bf16 token-order (4 MB)
    unsigned short* hg  = xb + (size_t)TOK * DM;             // [4096][2048] bf16 grouped (16 MB)
    unsigned short* W1t = hg + (size_t)TOK * HF;             // [E][HF][DM]  bf16 (16.8 MB)
    unsigned short* W2t = W1t + (size_t)NE * HF * DM;        // [E][DM][HF]  bf16 (16.8 MB)
    float* pbuf = (float*)(W2t + (size_t)NE * DM * HF);      // [2][4096][512] fp32 (16.8 MB)
    // FC2 A-tile overruns past hg end land in W1t (valid memory, non-NaN bf16);
    // rows >= cnt never stored. FC1 A rows are perm-clamped (no overrun).
    // YT=16 with 64-row tiles covers cnt up to 1024 (>20 sigma above 512 mean).

    // 1: router (+ token-order bf16 x) || W1 transpose (XCD-pinned writers)
    k_router_trW1<<<TOK / 4 + 2048, 256, 0, stream>>>(x, Wr, br, W1, routes, xb, W1t);
    // 2: ballot organize (1 block, ~2 us)
    k_organize<<<1, 1024, 0, stream>>>(routes, offsets, perm);
    // 3: fc1 (perm-gather in A staging), 64x128 tiles, expert->XCD grid:
    //    ids 0..2047 GEMM (16x * 16y per expert), ids 2048..4095 W2 transpose
    k_gemm<DM, HF, true, 1, 16, 16><<<NE * 256 + 2048, 256, 0, stream>>>(
        xb, W1t, b1, hg, nullptr, offsets, perm, W2, W2t);
    // 4: fc2, split-K=2, 64x128 tiles, expert->XCD grid (4x * 16y * 2ks)
    k_gemm<HF, DM, false, 2, 4, 16><<<NE * 128, 256, 0, stream>>>(
        hg, W2t, nullptr, nullptr, pbuf, offsets, perm, nullptr, nullptr);
    // 5: reduce + bias + scatter (2 partials)
    k_reduce<<<TOK, 128, 0, stream>>>(pbuf, perm, offsets, b2, out);
}